// Round 1
// baseline (2054.297 us; speedup 1.0000x reference)
//
#include <hip/hip_runtime.h>
#include <stdint.h>

#define DIM   1024
#define DEPTH 6
#define HEADS 16
#define FF    4096
#define SEQ   1024
#define BATCH 2
#define ROWS  (BATCH*SEQ)   // 2048
#define DH    64            // head dim

typedef __bf16 bf16x8 __attribute__((ext_vector_type(8)));
typedef float  f32x4  __attribute__((ext_vector_type(4)));

__device__ __forceinline__ unsigned short f2bf(float f) {
  unsigned int u = __builtin_bit_cast(unsigned int, f);
  u += 0x7fff + ((u >> 16) & 1);          // round-to-nearest-even
  return (unsigned short)(u >> 16);
}
__device__ __forceinline__ float bf2f(unsigned short h) {
  unsigned int u = ((unsigned int)h) << 16;
  return __builtin_bit_cast(float, u);
}

// async global->LDS, 16 bytes per lane. LDS dest must be uniform-base + lane*16.
__device__ __forceinline__ void async_load16(const void* g, void* l) {
  __builtin_amdgcn_global_load_lds(
      (const __attribute__((address_space(1))) unsigned int*)g,
      (__attribute__((address_space(3))) unsigned int*)l, 16, 0, 0);
}

// ---------------------------------------------------------------------------
// GEMM: C[M,N] = A[M,K] @ B^T  where B is stored [N][K] (bf16, K contiguous).
// BK=64, 256 threads (4 waves). 16x16x32 bf16 MFMA.
// EPI: 0 = store bf16
//      1 = store bf16 of (acc*scale + bias2[zh][m][n])        (attn scores)
//      2 = Cf[m][n] += acc + bias1[n]                         (residual adds)
//      3 = store bf16 of gelu(acc + bias1[n])                 (FFN mid)
// Batched via blockIdx.z: z -> (zb = z/ZH, zh = z%ZH), per-operand strides.
// ---------------------------------------------------------------------------
template<int BM, int BN, int EPI>
__global__ void __launch_bounds__(256, 2)
gemm_kernel(const unsigned short* __restrict__ A, long lda,
            const unsigned short* __restrict__ B, long ldb,
            unsigned short* __restrict__ Cb, float* __restrict__ Cf, long ldc,
            const float* __restrict__ bias1, const float* __restrict__ bias2,
            float scale, int K, int ZH,
            long sAb, long sAh, long sBb, long sBh, long sCb, long sCh,
            long sBiasH)
{
  constexpr int BK = 64;
  int z  = blockIdx.z;
  int zb = z / ZH, zh = z % ZH;
  A += zb * sAb + zh * sAh;
  B += zb * sBb + zh * sBh;
  const long coff = (long)zb * sCb + (long)zh * sCh;

  __shared__ unsigned short As[BM * BK];
  __shared__ unsigned short Bs[BN * BK];

  const int tid  = threadIdx.x;
  const int row0 = blockIdx.x * BM;
  const int col0 = blockIdx.y * BN;

  constexpr int WGN = (BN >= 128) ? 2 : 1;   // waves along N
  constexpr int WGM = 4 / WGN;               // waves along M
  constexpr int WTM = BM / WGM;              // wave tile M (64 or 32)
  constexpr int WTN = BN / WGN;              // wave tile N (64)
  constexpr int ITM = WTM / 16;
  constexpr int ITN = WTN / 16;

  const int w = tid >> 6, l = tid & 63;
  const int quad = l >> 4, r16 = l & 15;
  const int wm = (w / WGN) * WTM;
  const int wn = (w % WGN) * WTN;

  f32x4 acc[ITM][ITN] = {};

  constexpr int APASS = (BM * 8) / 256;      // 16B chunks per thread for A tile
  constexpr int BPASS = (BN * 8) / 256;

  const unsigned short* Ag = A + (long)row0 * lda;
  const unsigned short* Bg = B + (long)col0 * ldb;

  for (int k0 = 0; k0 < K; k0 += BK) {
#pragma unroll
    for (int p = 0; p < APASS; p++) {
      int flat = p * 256 + tid;
      int r = flat >> 3, c8 = (flat & 7) * 8;
      async_load16(Ag + (long)r * lda + k0 + c8, &As[flat * 8]);
    }
#pragma unroll
    for (int p = 0; p < BPASS; p++) {
      int flat = p * 256 + tid;
      int r = flat >> 3, c8 = (flat & 7) * 8;
      async_load16(Bg + (long)r * ldb + k0 + c8, &Bs[flat * 8]);
    }
    __syncthreads();   // drains vmcnt: LDS now holds the tiles
#pragma unroll
    for (int ks = 0; ks < 2; ks++) {
      bf16x8 af[ITM], bfr[ITN];
#pragma unroll
      for (int i = 0; i < ITM; i++)
        af[i] = *(const bf16x8*)&As[(wm + i * 16 + r16) * BK + ks * 32 + quad * 8];
#pragma unroll
      for (int j = 0; j < ITN; j++)
        bfr[j] = *(const bf16x8*)&Bs[(wn + j * 16 + r16) * BK + ks * 32 + quad * 8];
#pragma unroll
      for (int i = 0; i < ITM; i++)
#pragma unroll
        for (int j = 0; j < ITN; j++)
          acc[i][j] = __builtin_amdgcn_mfma_f32_16x16x32_bf16(af[i], bfr[j], acc[i][j], 0, 0, 0);
    }
    __syncthreads();
  }

  // epilogue: C/D layout row = quad*4 + reg, col = lane&15
#pragma unroll
  for (int i = 0; i < ITM; i++) {
#pragma unroll
    for (int j = 0; j < ITN; j++) {
      const int rr = row0 + wm + i * 16 + quad * 4;
      const int cc = col0 + wn + j * 16 + r16;
#pragma unroll
      for (int r = 0; r < 4; r++) {
        const long idx = (long)(rr + r) * ldc + cc;
        float v = acc[i][j][r];
        if constexpr (EPI == 0) {
          Cb[coff + idx] = f2bf(v);
        } else if constexpr (EPI == 1) {
          v = v * scale + bias2[(long)zh * sBiasH + idx];
          Cb[coff + idx] = f2bf(v);
        } else if constexpr (EPI == 2) {
          Cf[coff + idx] += v + bias1[cc];
        } else if constexpr (EPI == 3) {
          v += bias1[cc];
          float gl = 0.5f * v * (1.0f + erff(v * 0.70710678118654752f));
          Cb[coff + idx] = f2bf(gl);
        }
      }
    }
  }
}

// ---------------------------------------------------------------------------
// LayerNorm: one block (256 thr) per row of 1024 fp32 -> bf16 out
// ---------------------------------------------------------------------------
__global__ void k_layernorm(const float* __restrict__ x, const float* __restrict__ g,
                            const float* __restrict__ b, unsigned short* __restrict__ out)
{
  const int row = blockIdx.x;
  const int t = threadIdx.x;
  float4 v = ((const float4*)(x + (long)row * DIM))[t];
  float s = v.x + v.y + v.z + v.w;
  float q = v.x * v.x + v.y * v.y + v.z * v.z + v.w * v.w;
#pragma unroll
  for (int off = 32; off > 0; off >>= 1) {
    s += __shfl_down(s, off);
    q += __shfl_down(q, off);
  }
  __shared__ float shs[4], shq[4];
  if ((t & 63) == 0) { shs[t >> 6] = s; shq[t >> 6] = q; }
  __syncthreads();
  s = shs[0] + shs[1] + shs[2] + shs[3];
  q = shq[0] + shq[1] + shq[2] + shq[3];
  const float mu  = s * (1.0f / DIM);
  const float var = q * (1.0f / DIM) - mu * mu;
  const float rs  = rsqrtf(var + 1e-5f);
  float4 gg = ((const float4*)g)[t];
  float4 bb = ((const float4*)b)[t];
  ushort4 o;
  o.x = f2bf((v.x - mu) * rs * gg.x + bb.x);
  o.y = f2bf((v.y - mu) * rs * gg.y + bb.y);
  o.z = f2bf((v.z - mu) * rs * gg.z + bb.z);
  o.w = f2bf((v.w - mu) * rs * gg.w + bb.w);
  ((ushort4*)out)[(long)row * (DIM / 4) + t] = o;
}

// ---------------------------------------------------------------------------
// Row softmax over 1024 bf16, in place. One block per row.
// ---------------------------------------------------------------------------
__global__ void k_softmax(unsigned short* __restrict__ S)
{
  const long row = blockIdx.x;
  unsigned short* sr = S + row * SEQ;
  const int t = threadIdx.x;
  ushort4 u = ((ushort4*)sr)[t];
  float a0 = bf2f(u.x), a1 = bf2f(u.y), a2 = bf2f(u.z), a3 = bf2f(u.w);
  float mx = fmaxf(fmaxf(a0, a1), fmaxf(a2, a3));
#pragma unroll
  for (int off = 32; off > 0; off >>= 1) mx = fmaxf(mx, __shfl_down(mx, off));
  __shared__ float sh[4];
  if ((t & 63) == 0) sh[t >> 6] = mx;
  __syncthreads();
  mx = fmaxf(fmaxf(sh[0], sh[1]), fmaxf(sh[2], sh[3]));
  __syncthreads();
  float e0 = __expf(a0 - mx), e1 = __expf(a1 - mx), e2 = __expf(a2 - mx), e3 = __expf(a3 - mx);
  float s = e0 + e1 + e2 + e3;
#pragma unroll
  for (int off = 32; off > 0; off >>= 1) s += __shfl_down(s, off);
  if ((t & 63) == 0) sh[t >> 6] = s;
  __syncthreads();
  s = sh[0] + sh[1] + sh[2] + sh[3];
  const float inv = 1.0f / s;
  u.x = f2bf(e0 * inv); u.y = f2bf(e1 * inv); u.z = f2bf(e2 * inv); u.w = f2bf(e3 * inv);
  ((ushort4*)sr)[t] = u;
}

// ---------------------------------------------------------------------------
// Weight transpose+convert: w[K][N] fp32 -> wT[N][K] bf16. block (64,4), tile 64x64.
// ---------------------------------------------------------------------------
__global__ void k_wtrans(const float* __restrict__ w, unsigned short* __restrict__ wT,
                         int K, int N)
{
  __shared__ unsigned short tile[64][65];
  const int n0 = blockIdx.x * 64, k0 = blockIdx.y * 64;
  const int tx = threadIdx.x, ty = threadIdx.y;
#pragma unroll
  for (int i = 0; i < 16; i++)
    tile[ty + 4 * i][tx] = f2bf(w[(long)(k0 + ty + 4 * i) * N + n0 + tx]);
  __syncthreads();
#pragma unroll
  for (int i = 0; i < 16; i++)
    wT[(long)(n0 + ty + 4 * i) * K + k0 + tx] = tile[tx][ty + 4 * i];
}

// ---------------------------------------------------------------------------
// V transpose: qkv[b, n, 2*DIM + h*64 + d] (bf16) -> vT[(b*16+h)][d][n]
// ---------------------------------------------------------------------------
__global__ void k_vtrans(const unsigned short* __restrict__ qkv, unsigned short* __restrict__ vT)
{
  __shared__ unsigned short tile[64][65];
  const int z = blockIdx.z;
  const int b_ = z >> 4, h_ = z & 15;
  const int n0 = blockIdx.x * 64;
  const int tx = threadIdx.x, ty = threadIdx.y;
  const unsigned short* src = qkv + (long)b_ * SEQ * (3 * DIM) + 2 * DIM + h_ * DH;
#pragma unroll
  for (int i = 0; i < 16; i++)
    tile[ty + 4 * i][tx] = src[(long)(n0 + ty + 4 * i) * (3 * DIM) + tx];
  __syncthreads();
  unsigned short* dst = vT + (long)z * DH * SEQ;
#pragma unroll
  for (int i = 0; i < 16; i++)
    dst[(long)(ty + 4 * i) * SEQ + n0 + tx] = tile[tx][ty + 4 * i];
}

// ---------------------------------------------------------------------------
extern "C" void kernel_launch(void* const* d_in, const int* in_sizes, int n_in,
                              void* d_out, int out_size, void* d_ws, size_t ws_size,
                              hipStream_t stream)
{
  const float* x0   = (const float*)d_in[0];
  const float* rpb  = (const float*)d_in[1];
  const float* ln1g = (const float*)d_in[2];
  const float* ln1b = (const float*)d_in[3];
  const float* wqkv = (const float*)d_in[4];
  const float* wout = (const float*)d_in[5];
  const float* bout = (const float*)d_in[6];
  const float* ln2g = (const float*)d_in[7];
  const float* ln2b = (const float*)d_in[8];
  const float* w1   = (const float*)d_in[9];
  const float* b1   = (const float*)d_in[10];
  const float* w2   = (const float*)d_in[11];
  const float* b2   = (const float*)d_in[12];
  float* x = (float*)d_out;   // running residual stream (fp32), doubles as output

  // workspace layout (~128 MB total)
  char* p = (char*)d_ws;
  auto alloc = [&](size_t n) { char* r = p; p += (n + 255) & ~(size_t)255; return r; };
  unsigned short* wTqkv = (unsigned short*)alloc((size_t)3 * DIM * DIM * 2);
  unsigned short* wTout = (unsigned short*)alloc((size_t)DIM * DIM * 2);
  unsigned short* wT1   = (unsigned short*)alloc((size_t)FF * DIM * 2);
  unsigned short* wT2   = (unsigned short*)alloc((size_t)DIM * FF * 2);
  unsigned short* hbuf  = (unsigned short*)alloc((size_t)ROWS * DIM * 2);
  unsigned short* qkvb  = (unsigned short*)alloc((size_t)ROWS * 3 * DIM * 2);
  unsigned short* Sbuf  = (unsigned short*)alloc((size_t)BATCH * HEADS * SEQ * SEQ * 2);
  unsigned short* vTb   = (unsigned short*)alloc((size_t)BATCH * HEADS * DH * SEQ * 2);
  unsigned short* obuf  = (unsigned short*)alloc((size_t)ROWS * DIM * 2);
  unsigned short* ffnb  = (unsigned short*)alloc((size_t)ROWS * FF * 2);

  hipMemcpyAsync(x, x0, (size_t)ROWS * DIM * 4, hipMemcpyDeviceToDevice, stream);

  const dim3 tb(64, 4);
  for (int l = 0; l < DEPTH; l++) {
    const float* Wqkv = wqkv + (size_t)l * DIM * 3 * DIM;
    const float* Wout = wout + (size_t)l * DIM * DIM;
    const float* W1   = w1   + (size_t)l * DIM * FF;
    const float* W2   = w2   + (size_t)l * FF * DIM;

    k_wtrans<<<dim3(3 * DIM / 64, DIM / 64), tb, 0, stream>>>(Wqkv, wTqkv, DIM, 3 * DIM);
    k_wtrans<<<dim3(DIM / 64, DIM / 64),     tb, 0, stream>>>(Wout, wTout, DIM, DIM);
    k_wtrans<<<dim3(FF / 64, DIM / 64),      tb, 0, stream>>>(W1,   wT1,   DIM, FF);
    k_wtrans<<<dim3(DIM / 64, FF / 64),      tb, 0, stream>>>(W2,   wT2,   FF, DIM);

    // ---- attention ----
    k_layernorm<<<ROWS, 256, 0, stream>>>(x, ln1g + l * DIM, ln1b + l * DIM, hbuf);

    gemm_kernel<128, 128, 0><<<dim3(ROWS / 128, 3 * DIM / 128, 1), 256, 0, stream>>>(
        hbuf, DIM, wTqkv, DIM, qkvb, nullptr, 3 * DIM, nullptr, nullptr, 1.0f, DIM,
        1, 0, 0, 0, 0, 0, 0, 0);

    // scores: per (b,h): q[n,64] @ k[n,64]^T * 0.125 + rpb[h]  -> bf16 S
    gemm_kernel<128, 128, 1><<<dim3(SEQ / 128, SEQ / 128, BATCH * HEADS), 256, 0, stream>>>(
        qkvb, 3 * DIM, qkvb + DIM, 3 * DIM, Sbuf, nullptr, SEQ, nullptr, rpb, 0.125f, DH,
        HEADS, (long)SEQ * 3 * DIM, DH, (long)SEQ * 3 * DIM, DH,
        (long)HEADS * SEQ * SEQ, (long)SEQ * SEQ, (long)SEQ * SEQ);

    k_softmax<<<BATCH * HEADS * SEQ, 256, 0, stream>>>(Sbuf);

    k_vtrans<<<dim3(SEQ / 64, 1, BATCH * HEADS), tb, 0, stream>>>(qkvb, vTb);

    // o[b, n, h*64+d] = P @ v   (B^T = vT[d][n])
    gemm_kernel<128, 64, 0><<<dim3(SEQ / 128, 1, BATCH * HEADS), 256, 0, stream>>>(
        Sbuf, SEQ, vTb, SEQ, obuf, nullptr, DIM, nullptr, nullptr, 1.0f, SEQ,
        HEADS, (long)HEADS * SEQ * SEQ, (long)SEQ * SEQ,
        (long)HEADS * DH * SEQ, (long)DH * SEQ, (long)SEQ * DIM, (long)DH, 0);

    // x += o @ w_out + b_out
    gemm_kernel<128, 128, 2><<<dim3(ROWS / 128, DIM / 128, 1), 256, 0, stream>>>(
        obuf, DIM, wTout, DIM, nullptr, x, DIM, bout + l * DIM, nullptr, 1.0f, DIM,
        1, 0, 0, 0, 0, 0, 0, 0);

    // ---- FFN ----
    k_layernorm<<<ROWS, 256, 0, stream>>>(x, ln2g + l * DIM, ln2b + l * DIM, hbuf);

    gemm_kernel<128, 128, 3><<<dim3(ROWS / 128, FF / 128, 1), 256, 0, stream>>>(
        hbuf, DIM, wT1, DIM, ffnb, nullptr, FF, b1 + l * FF, nullptr, 1.0f, DIM,
        1, 0, 0, 0, 0, 0, 0, 0);

    gemm_kernel<128, 128, 2><<<dim3(ROWS / 128, DIM / 128, 1), 256, 0, stream>>>(
        ffnb, FF, wT2, FF, nullptr, x, DIM, b2 + l * DIM, nullptr, 1.0f, FF,
        1, 0, 0, 0, 0, 0, 0, 0);
  }
}

// Round 2
// 1569.816 us; speedup vs baseline: 1.3086x; 1.3086x over previous
//
#include <hip/hip_runtime.h>
#include <stdint.h>

#define DIM   1024
#define DEPTH 6
#define HEADS 16
#define FF    4096
#define SEQ   1024
#define BATCH 2
#define ROWS  (BATCH*SEQ)   // 2048
#define DH    64            // head dim

typedef __bf16 bf16x8 __attribute__((ext_vector_type(8)));
typedef float  f32x4  __attribute__((ext_vector_type(4)));

__device__ __forceinline__ unsigned short f2bf(float f) {
  unsigned int u = __builtin_bit_cast(unsigned int, f);
  u += 0x7fff + ((u >> 16) & 1);          // round-to-nearest-even
  return (unsigned short)(u >> 16);
}
__device__ __forceinline__ float bf2f(unsigned short h) {
  unsigned int u = ((unsigned int)h) << 16;
  return __builtin_bit_cast(float, u);
}

// async global->LDS, 16 bytes per lane. LDS dest must be uniform-base + lane*16.
__device__ __forceinline__ void async_load16(const void* g, void* l) {
  __builtin_amdgcn_global_load_lds(
      (const __attribute__((address_space(1))) unsigned int*)g,
      (__attribute__((address_space(3))) unsigned int*)l, 16, 0, 0);
}

// ---------------------------------------------------------------------------
// GEMM: C[M,N] = A[M,K] @ B^T  where B is stored [N][K] (bf16, K contiguous).
// BK=64, 256 threads (4 waves). 16x16x32 bf16 MFMA.
// LDS tiles XOR-swizzled: 16B chunk c of row r lives at chunk (c ^ (r&7)).
// EPI: 0 = store bf16
//      1 = store bf16 of (acc*scale + bias2[zh][m][n])        (attn scores)
//      2 = Cf[m][n] += acc + bias1[n]                         (residual adds)
//      3 = store bf16 of gelu(acc + bias1[n])                 (FFN mid)
// Batched via blockIdx.z: z -> (zb = z/ZH, zh = z%ZH), per-operand strides.
// ---------------------------------------------------------------------------
template<int BM, int BN, int EPI>
__global__ void __launch_bounds__(256, 4)
gemm_kernel(const unsigned short* __restrict__ A, long lda,
            const unsigned short* __restrict__ B, long ldb,
            unsigned short* __restrict__ Cb, float* __restrict__ Cf, long ldc,
            const float* __restrict__ bias1, const float* __restrict__ bias2,
            float scale, int K, int ZH,
            long sAb, long sAh, long sBb, long sBh, long sCb, long sCh,
            long sBiasH)
{
  constexpr int BK = 64;                    // 8 chunks of 16B per row
  int z  = blockIdx.z;
  int zb = z / ZH, zh = z % ZH;
  A += zb * sAb + zh * sAh;
  B += zb * sBb + zh * sBh;
  const long coff = (long)zb * sCb + (long)zh * sCh;

  __shared__ unsigned short As[BM * BK];
  __shared__ unsigned short Bs[BN * BK];

  const int tid  = threadIdx.x;
  const int row0 = blockIdx.x * BM;
  const int col0 = blockIdx.y * BN;

  constexpr int WGN = 2;                    // waves along N
  constexpr int WGM = 2;                    // waves along M
  constexpr int WTM = BM / WGM;             // wave tile M
  constexpr int WTN = BN / WGN;             // wave tile N
  constexpr int ITM = WTM / 16;
  constexpr int ITN = WTN / 16;

  const int w = tid >> 6, l = tid & 63;
  const int quad = l >> 4, r16 = l & 15;
  const int wm = (w / WGN) * WTM;
  const int wn = (w % WGN) * WTN;
  const int sw = r16 & 7;                   // read-side XOR swizzle key

  f32x4 acc[ITM][ITN] = {};

  constexpr int APASS = (BM * 8) / 256;     // 16B chunks per thread for A tile
  constexpr int BPASS = (BN * 8) / 256;

  const unsigned short* Ag = A + (long)row0 * lda;
  const unsigned short* Bg = B + (long)col0 * ldb;

  for (int k0 = 0; k0 < K; k0 += BK) {
#pragma unroll
    for (int p = 0; p < APASS; p++) {
      int flat = p * 256 + tid;
      int r = flat >> 3, cl = flat & 7;
      int cg = cl ^ (r & 7);                // fetch the chunk that belongs at slot cl
      async_load16(Ag + (long)r * lda + k0 + cg * 8, &As[flat * 8]);
    }
#pragma unroll
    for (int p = 0; p < BPASS; p++) {
      int flat = p * 256 + tid;
      int r = flat >> 3, cl = flat & 7;
      int cg = cl ^ (r & 7);
      async_load16(Bg + (long)r * ldb + k0 + cg * 8, &Bs[flat * 8]);
    }
    __syncthreads();   // drains vmcnt: LDS now holds the tiles
#pragma unroll
    for (int ks = 0; ks < 2; ks++) {
      const int c = ks * 4 + quad;          // logical 16B chunk index
      bf16x8 af[ITM], bfr[ITN];
#pragma unroll
      for (int i = 0; i < ITM; i++)
        af[i] = *(const bf16x8*)&As[(wm + i * 16 + r16) * BK + (c ^ sw) * 8];
#pragma unroll
      for (int j = 0; j < ITN; j++)
        bfr[j] = *(const bf16x8*)&Bs[(wn + j * 16 + r16) * BK + (c ^ sw) * 8];
#pragma unroll
      for (int i = 0; i < ITM; i++)
#pragma unroll
        for (int j = 0; j < ITN; j++)
          acc[i][j] = __builtin_amdgcn_mfma_f32_16x16x32_bf16(af[i], bfr[j], acc[i][j], 0, 0, 0);
    }
    __syncthreads();
  }

  // epilogue: C/D layout row = quad*4 + reg, col = lane&15
#pragma unroll
  for (int i = 0; i < ITM; i++) {
#pragma unroll
    for (int j = 0; j < ITN; j++) {
      const int rr = row0 + wm + i * 16 + quad * 4;
      const int cc = col0 + wn + j * 16 + r16;
#pragma unroll
      for (int r = 0; r < 4; r++) {
        const long idx = (long)(rr + r) * ldc + cc;
        float v = acc[i][j][r];
        if constexpr (EPI == 0) {
          Cb[coff + idx] = f2bf(v);
        } else if constexpr (EPI == 1) {
          v = v * scale + bias2[(long)zh * sBiasH + idx];
          Cb[coff + idx] = f2bf(v);
        } else if constexpr (EPI == 2) {
          Cf[coff + idx] += v + bias1[cc];
        } else if constexpr (EPI == 3) {
          v += bias1[cc];
          float gl = 0.5f * v * (1.0f + erff(v * 0.70710678118654752f));
          Cb[coff + idx] = f2bf(gl);
        }
      }
    }
  }
}

// ---------------------------------------------------------------------------
// LayerNorm: one block (256 thr) per row of 1024 fp32 -> bf16 out
// ---------------------------------------------------------------------------
__global__ void k_layernorm(const float* __restrict__ x, const float* __restrict__ g,
                            const float* __restrict__ b, unsigned short* __restrict__ out)
{
  const int row = blockIdx.x;
  const int t = threadIdx.x;
  float4 v = ((const float4*)(x + (long)row * DIM))[t];
  float s = v.x + v.y + v.z + v.w;
  float q = v.x * v.x + v.y * v.y + v.z * v.z + v.w * v.w;
#pragma unroll
  for (int off = 32; off > 0; off >>= 1) {
    s += __shfl_down(s, off);
    q += __shfl_down(q, off);
  }
  __shared__ float shs[4], shq[4];
  if ((t & 63) == 0) { shs[t >> 6] = s; shq[t >> 6] = q; }
  __syncthreads();
  s = shs[0] + shs[1] + shs[2] + shs[3];
  q = shq[0] + shq[1] + shq[2] + shq[3];
  const float mu  = s * (1.0f / DIM);
  const float var = q * (1.0f / DIM) - mu * mu;
  const float rs  = rsqrtf(var + 1e-5f);
  float4 gg = ((const float4*)g)[t];
  float4 bb = ((const float4*)b)[t];
  ushort4 o;
  o.x = f2bf((v.x - mu) * rs * gg.x + bb.x);
  o.y = f2bf((v.y - mu) * rs * gg.y + bb.y);
  o.z = f2bf((v.z - mu) * rs * gg.z + bb.z);
  o.w = f2bf((v.w - mu) * rs * gg.w + bb.w);
  ((ushort4*)out)[(long)row * (DIM / 4) + t] = o;
}

// ---------------------------------------------------------------------------
// Row softmax over 1024 bf16, in place. One block per row.
// ---------------------------------------------------------------------------
__global__ void k_softmax(unsigned short* __restrict__ S)
{
  const long row = blockIdx.x;
  unsigned short* sr = S + row * SEQ;
  const int t = threadIdx.x;
  ushort4 u = ((ushort4*)sr)[t];
  float a0 = bf2f(u.x), a1 = bf2f(u.y), a2 = bf2f(u.z), a3 = bf2f(u.w);
  float mx = fmaxf(fmaxf(a0, a1), fmaxf(a2, a3));
#pragma unroll
  for (int off = 32; off > 0; off >>= 1) mx = fmaxf(mx, __shfl_down(mx, off));
  __shared__ float sh[4];
  if ((t & 63) == 0) sh[t >> 6] = mx;
  __syncthreads();
  mx = fmaxf(fmaxf(sh[0], sh[1]), fmaxf(sh[2], sh[3]));
  __syncthreads();
  float e0 = __expf(a0 - mx), e1 = __expf(a1 - mx), e2 = __expf(a2 - mx), e3 = __expf(a3 - mx);
  float s = e0 + e1 + e2 + e3;
#pragma unroll
  for (int off = 32; off > 0; off >>= 1) s += __shfl_down(s, off);
  if ((t & 63) == 0) sh[t >> 6] = s;
  __syncthreads();
  s = sh[0] + sh[1] + sh[2] + sh[3];
  const float inv = 1.0f / s;
  u.x = f2bf(e0 * inv); u.y = f2bf(e1 * inv); u.z = f2bf(e2 * inv); u.w = f2bf(e3 * inv);
  ((ushort4*)sr)[t] = u;
}

// ---------------------------------------------------------------------------
// Weight transpose+convert: w[K][N] fp32 -> wT[N][K] bf16. block (64,4), tile 64x64.
// ---------------------------------------------------------------------------
__global__ void k_wtrans(const float* __restrict__ w, unsigned short* __restrict__ wT,
                         int K, int N)
{
  __shared__ unsigned short tile[64][65];
  const int n0 = blockIdx.x * 64, k0 = blockIdx.y * 64;
  const int tx = threadIdx.x, ty = threadIdx.y;
#pragma unroll
  for (int i = 0; i < 16; i++)
    tile[ty + 4 * i][tx] = f2bf(w[(long)(k0 + ty + 4 * i) * N + n0 + tx]);
  __syncthreads();
#pragma unroll
  for (int i = 0; i < 16; i++)
    wT[(long)(n0 + ty + 4 * i) * K + k0 + tx] = tile[tx][ty + 4 * i];
}

// ---------------------------------------------------------------------------
// V transpose: qkv[b, n, 2*DIM + h*64 + d] (bf16) -> vT[(b*16+h)][d][n]
// ---------------------------------------------------------------------------
__global__ void k_vtrans(const unsigned short* __restrict__ qkv, unsigned short* __restrict__ vT)
{
  __shared__ unsigned short tile[64][65];
  const int z = blockIdx.z;
  const int b_ = z >> 4, h_ = z & 15;
  const int n0 = blockIdx.x * 64;
  const int tx = threadIdx.x, ty = threadIdx.y;
  const unsigned short* src = qkv + (long)b_ * SEQ * (3 * DIM) + 2 * DIM + h_ * DH;
#pragma unroll
  for (int i = 0; i < 16; i++)
    tile[ty + 4 * i][tx] = src[(long)(n0 + ty + 4 * i) * (3 * DIM) + tx];
  __syncthreads();
  unsigned short* dst = vT + (long)z * DH * SEQ;
#pragma unroll
  for (int i = 0; i < 16; i++)
    dst[(long)(ty + 4 * i) * SEQ + n0 + tx] = tile[tx][ty + 4 * i];
}

// ---------------------------------------------------------------------------
extern "C" void kernel_launch(void* const* d_in, const int* in_sizes, int n_in,
                              void* d_out, int out_size, void* d_ws, size_t ws_size,
                              hipStream_t stream)
{
  const float* x0   = (const float*)d_in[0];
  const float* rpb  = (const float*)d_in[1];
  const float* ln1g = (const float*)d_in[2];
  const float* ln1b = (const float*)d_in[3];
  const float* wqkv = (const float*)d_in[4];
  const float* wout = (const float*)d_in[5];
  const float* bout = (const float*)d_in[6];
  const float* ln2g = (const float*)d_in[7];
  const float* ln2b = (const float*)d_in[8];
  const float* w1   = (const float*)d_in[9];
  const float* b1   = (const float*)d_in[10];
  const float* w2   = (const float*)d_in[11];
  const float* b2   = (const float*)d_in[12];
  float* x = (float*)d_out;   // running residual stream (fp32), doubles as output

  // workspace layout (~128 MB total)
  char* p = (char*)d_ws;
  auto alloc = [&](size_t n) { char* r = p; p += (n + 255) & ~(size_t)255; return r; };
  unsigned short* wTqkv = (unsigned short*)alloc((size_t)3 * DIM * DIM * 2);
  unsigned short* wTout = (unsigned short*)alloc((size_t)DIM * DIM * 2);
  unsigned short* wT1   = (unsigned short*)alloc((size_t)FF * DIM * 2);
  unsigned short* wT2   = (unsigned short*)alloc((size_t)DIM * FF * 2);
  unsigned short* hbuf  = (unsigned short*)alloc((size_t)ROWS * DIM * 2);
  unsigned short* qkvb  = (unsigned short*)alloc((size_t)ROWS * 3 * DIM * 2);
  unsigned short* Sbuf  = (unsigned short*)alloc((size_t)BATCH * HEADS * SEQ * SEQ * 2);
  unsigned short* vTb   = (unsigned short*)alloc((size_t)BATCH * HEADS * DH * SEQ * 2);
  unsigned short* obuf  = (unsigned short*)alloc((size_t)ROWS * DIM * 2);
  unsigned short* ffnb  = (unsigned short*)alloc((size_t)ROWS * FF * 2);

  hipMemcpyAsync(x, x0, (size_t)ROWS * DIM * 4, hipMemcpyDeviceToDevice, stream);

  const dim3 tb(64, 4);
  for (int l = 0; l < DEPTH; l++) {
    const float* Wqkv = wqkv + (size_t)l * DIM * 3 * DIM;
    const float* Wout = wout + (size_t)l * DIM * DIM;
    const float* W1   = w1   + (size_t)l * DIM * FF;
    const float* W2   = w2   + (size_t)l * FF * DIM;

    k_wtrans<<<dim3(3 * DIM / 64, DIM / 64), tb, 0, stream>>>(Wqkv, wTqkv, DIM, 3 * DIM);
    k_wtrans<<<dim3(DIM / 64, DIM / 64),     tb, 0, stream>>>(Wout, wTout, DIM, DIM);
    k_wtrans<<<dim3(FF / 64, DIM / 64),      tb, 0, stream>>>(W1,   wT1,   DIM, FF);
    k_wtrans<<<dim3(DIM / 64, FF / 64),      tb, 0, stream>>>(W2,   wT2,   FF, DIM);

    // ---- attention ----
    k_layernorm<<<ROWS, 256, 0, stream>>>(x, ln1g + l * DIM, ln1b + l * DIM, hbuf);

    // qkv: 64x128 tiles -> 32*24 = 768 blocks
    gemm_kernel<64, 128, 0><<<dim3(ROWS / 64, 3 * DIM / 128, 1), 256, 0, stream>>>(
        hbuf, DIM, wTqkv, DIM, qkvb, nullptr, 3 * DIM, nullptr, nullptr, 1.0f, DIM,
        1, 0, 0, 0, 0, 0, 0, 0);

    // scores: per (b,h): q[n,64] @ k[n,64]^T * 0.125 + rpb[h] -> bf16 S  (2048 blocks)
    gemm_kernel<128, 128, 1><<<dim3(SEQ / 128, SEQ / 128, BATCH * HEADS), 256, 0, stream>>>(
        qkvb, 3 * DIM, qkvb + DIM, 3 * DIM, Sbuf, nullptr, SEQ, nullptr, rpb, 0.125f, DH,
        HEADS, (long)SEQ * 3 * DIM, DH, (long)SEQ * 3 * DIM, DH,
        (long)HEADS * SEQ * SEQ, (long)SEQ * SEQ, (long)SEQ * SEQ);

    k_softmax<<<BATCH * HEADS * SEQ, 256, 0, stream>>>(Sbuf);

    k_vtrans<<<dim3(SEQ / 64, 1, BATCH * HEADS), tb, 0, stream>>>(qkvb, vTb);

    // o = P @ v : 64x64 tiles -> 16*1*32 = 512 blocks
    gemm_kernel<64, 64, 0><<<dim3(SEQ / 64, 1, BATCH * HEADS), 256, 0, stream>>>(
        Sbuf, SEQ, vTb, SEQ, obuf, nullptr, DIM, nullptr, nullptr, 1.0f, SEQ,
        HEADS, (long)HEADS * SEQ * SEQ, (long)SEQ * SEQ,
        (long)HEADS * DH * SEQ, (long)DH * SEQ, (long)SEQ * DIM, (long)DH, 0);

    // x += o @ w_out + b_out : 64x64 tiles -> 32*16 = 512 blocks
    gemm_kernel<64, 64, 2><<<dim3(ROWS / 64, DIM / 64, 1), 256, 0, stream>>>(
        obuf, DIM, wTout, DIM, nullptr, x, DIM, bout + l * DIM, nullptr, 1.0f, DIM,
        1, 0, 0, 0, 0, 0, 0, 0);

    // ---- FFN ----
    k_layernorm<<<ROWS, 256, 0, stream>>>(x, ln2g + l * DIM, ln2b + l * DIM, hbuf);

    // FFN1: 128x128 -> 16*32 = 512 blocks
    gemm_kernel<128, 128, 3><<<dim3(ROWS / 128, FF / 128, 1), 256, 0, stream>>>(
        hbuf, DIM, wT1, DIM, ffnb, nullptr, FF, b1 + l * FF, nullptr, 1.0f, DIM,
        1, 0, 0, 0, 0, 0, 0, 0);

    // FFN2: 64x64 -> 32*16 = 512 blocks
    gemm_kernel<64, 64, 2><<<dim3(ROWS / 64, DIM / 64, 1), 256, 0, stream>>>(
        ffnb, FF, wT2, FF, nullptr, x, DIM, b2 + l * DIM, nullptr, 1.0f, FF,
        1, 0, 0, 0, 0, 0, 0, 0);
  }
}